// Round 21
// baseline (38.512 us; speedup 1.0000x reference)
//
#include <hip/hip_runtime.h>
#include <hip/hip_bf16.h>
#include <cmath>

// Round 21: "copy-regime" qmain — max TLP, minimum machinery.
//   Every design since r14 ran 4 waves/SIMD with big register budgets
//   (ILP-regime); all plateaued at ~4.4 TB/s. The 6.3-7.1 TB/s copy/fill
//   kernels run tiny-footprint at 8 waves/SIMD (TLP-regime). This kernel
//   tests that axis: 1 row/thread, NO LDS, NO barriers, NO MFMA; 16x
//   float4 own-row loads (line touches are adjacent instrs -> L1 absorbs,
//   no r6 overfetch), rolling 4-deep window, fp32 GEMV vs uniform s_load
//   W, in-register tail, coalesced store. waves_per_eu(8,8) = 64-VGPR cap.
//   qprep split kernel verbatim (validated r10-r20).

// ---- prep kernel: verbatim round-10 ----
__global__ __launch_bounds__(256) void qprep_kernel(
    const float* __restrict__ qw,   // [3][4][2]
    float* __restrict__ A_out)      // [81][4]
{
  __shared__ float sre[16][17];
  __shared__ float sim[16][17];
  __shared__ float M[4][16][16];
  const int tid = threadIdx.x;
  const int col = tid >> 4;
  const int u   = tid & 15;

  sre[col][u] = (u == col) ? 1.0f : 0.0f;
  sim[col][u] = 0.0f;
  __syncthreads();

#pragma unroll
  for (int l = 0; l < 3; ++l) {
#pragma unroll
    for (int w = 0; w < 4; ++w) {
      const int mask = 8 >> w;     // wire 0 = MSB
      float sh, ch, sh2, ch2;
      __sincosf(0.5f * qw[(l * 4 + w) * 2 + 0], &sh, &ch);    // RY
      __sincosf(0.5f * qw[(l * 4 + w) * 2 + 1], &sh2, &ch2);  // RZ
      const int ua = u & ~mask, ub = u | mask;
      const float ar = sre[col][ua], ai = sim[col][ua];
      const float br = sre[col][ub], bi = sim[col][ub];
      __syncthreads();
      float nr, ni;
      if (u & mask) { nr = sh * ar + ch * br; ni = sh * ai + ch * bi; }
      else          { nr = ch * ar - sh * br; ni = ch * ai - sh * bi; }
      float rr, ri;
      if (u & mask) { rr = ch2 * nr - sh2 * ni; ri = ch2 * ni + sh2 * nr; }
      else          { rr = ch2 * nr + sh2 * ni; ri = ch2 * ni - sh2 * nr; }
      sre[col][u] = rr; sim[col][u] = ri;
      __syncthreads();
    }
    int src = u;
    if (src & 1) src ^= 8;
    if (src & 2) src ^= 1;
    if (src & 4) src ^= 2;
    if (src & 8) src ^= 4;
    const float pr = sre[col][src], pi = sim[col][src];
    __syncthreads();
    sre[col][u] = pr; sim[col][u] = pi;
    __syncthreads();
  }

  for (int idx = tid; idx < 1024; idx += 256) {
    const int w = idx >> 8, s = (idx >> 4) & 15, t = idx & 15;
    const int mask = 8 >> w;
    float acc = 0.0f;
#pragma unroll
    for (int uu = 0; uu < 16; ++uu) {
      const float z = (uu & mask) ? -1.0f : 1.0f;
      acc += z * (sre[s][uu] * sre[t][uu] + sim[s][uu] * sim[t][uu]);
    }
    M[w][s][t] = acc;
  }
  __syncthreads();

  for (int idx = tid; idx < 324; idx += 256) {
    const int w = idx & 3, pq = idx >> 2;
    const int p = pq / 9, q = pq % 9;
    const int i0 = p / 3, i1 = p % 3, i2 = q / 3, i3 = q % 3;
    float acc = 0.0f;
#pragma unroll
    for (int comb = 0; comb < 16; ++comb) {
      int s = 0, t = 0;
      float coef = 0.0625f;
      int j;
      j = (comb >> 3) & 1; s |= j << 3; t |= ((i0 == 2) ? (j ^ 1) : j) << 3; if (i0 == 1 && j) coef = -coef;
      j = (comb >> 2) & 1; s |= j << 2; t |= ((i1 == 2) ? (j ^ 1) : j) << 2; if (i1 == 1 && j) coef = -coef;
      j = (comb >> 1) & 1; s |= j << 1; t |= ((i2 == 2) ? (j ^ 1) : j) << 1; if (i2 == 1 && j) coef = -coef;
      j = comb & 1;        s |= j;      t |= ((i3 == 2) ? (j ^ 1) : j);      if (i3 == 1 && j) coef = -coef;
      acc = fmaf(coef, M[w][s][t], acc);
    }
    A_out[idx] = acc;   // layout [pq*4 + w]
  }
}

// fast tanh: 1 - 2*rcp(e^{2a}+1); err ~1ulp vs 1.98e-2 threshold
__device__ __forceinline__ float ftanh(float a) {
  return 1.0f - 2.0f * __builtin_amdgcn_rcpf(__expf(2.0f * a) + 1.0f);
}

// one 16-feature chunk of the 4 dot products; W reads wave-uniform (s_load)
#define DOT(V, I) {                                                         \
  const float4 w0_ = W4[0 * 16 + (I)];                                      \
  const float4 w1_ = W4[1 * 16 + (I)];                                      \
  const float4 w2_ = W4[2 * 16 + (I)];                                      \
  const float4 w3_ = W4[3 * 16 + (I)];                                      \
  a0 = fmaf(V.x, w0_.x, a0); a0 = fmaf(V.y, w0_.y, a0);                     \
  a0 = fmaf(V.z, w0_.z, a0); a0 = fmaf(V.w, w0_.w, a0);                     \
  a1 = fmaf(V.x, w1_.x, a1); a1 = fmaf(V.y, w1_.y, a1);                     \
  a1 = fmaf(V.z, w1_.z, a1); a1 = fmaf(V.w, w1_.w, a1);                     \
  a2 = fmaf(V.x, w2_.x, a2); a2 = fmaf(V.y, w2_.y, a2);                     \
  a2 = fmaf(V.z, w2_.z, a2); a2 = fmaf(V.w, w2_.w, a2);                     \
  a3 = fmaf(V.x, w3_.x, a3); a3 = fmaf(V.y, w3_.y, a3);                     \
  a3 = fmaf(V.z, w3_.z, a3); a3 = fmaf(V.w, w3_.w, a3); }

__global__ __launch_bounds__(256)
__attribute__((amdgpu_waves_per_eu(8, 8)))   // hard 64-VGPR cap: 8 waves/SIMD
void qmain_kernel(
    const float* __restrict__ x,     // [B][64]
    const float* __restrict__ Wp,    // [4][64]
    const float* __restrict__ bp,    // [4]
    const float4* __restrict__ Aws,  // [81] float4 (d_ws)
    float* __restrict__ out)         // [B][4]
{
  const size_t row = (size_t)blockIdx.x * 256 + threadIdx.x;
  const float4* xr = reinterpret_cast<const float4*>(x) + row * 16;
  const float4* W4 = reinterpret_cast<const float4*>(Wp);

  // rolling 4-deep load window: 4 KB/wave in flight; 32 waves/CU -> ~128 KB
  float4 v0 = xr[0], v1 = xr[1], v2 = xr[2], v3 = xr[3];
  float a0 = 0.f, a1 = 0.f, a2 = 0.f, a3 = 0.f;

  DOT(v0, 0);  v0 = xr[4];
  DOT(v1, 1);  v1 = xr[5];
  DOT(v2, 2);  v2 = xr[6];
  DOT(v3, 3);  v3 = xr[7];
  DOT(v0, 4);  v0 = xr[8];
  DOT(v1, 5);  v1 = xr[9];
  DOT(v2, 6);  v2 = xr[10];
  DOT(v3, 7);  v3 = xr[11];
  DOT(v0, 8);  v0 = xr[12];
  DOT(v1, 9);  v1 = xr[13];
  DOT(v2, 10); v2 = xr[14];
  DOT(v3, 11); v3 = xr[15];
  DOT(v0, 12);
  DOT(v1, 13);
  DOT(v2, 14);
  DOT(v3, 15);

  // ---- tail: tanh, sincos, g/h, 81-term contraction vs s_load'ed A ----
  const float t0 = ftanh(a0 + bp[0]);
  const float t1 = ftanh(a1 + bp[1]);
  const float t2 = ftanh(a2 + bp[2]);
  const float t3 = ftanh(a3 + bp[3]);

  float c0, s0, c1, s1, c2, s2, c3, s3;
  __sincosf(t0, &s0, &c0); __sincosf(t1, &s1, &c1);
  __sincosf(t2, &s2, &c2); __sincosf(t3, &s3, &c3);

  const float g[9] = {1.f, c1, s1, c0, c0 * c1, c0 * s1, s0, s0 * c1, s0 * s1};
  const float h[9] = {1.f, c3, s3, c2, c2 * c3, c2 * s3, s2, s2 * c3, s2 * s3};

  float e0 = 0.f, e1 = 0.f, e2 = 0.f, e3 = 0.f;
#pragma unroll
  for (int p = 0; p < 9; ++p) {
#pragma unroll
    for (int q = 0; q < 9; ++q) {
      const float4 a4 = Aws[p * 9 + q];   // uniform s_load, K$
      const float tt = g[p] * h[q];
      e0 = fmaf(a4.x, tt, e0); e1 = fmaf(a4.y, tt, e1);
      e2 = fmaf(a4.z, tt, e2); e3 = fmaf(a4.w, tt, e3);
    }
  }
  reinterpret_cast<float4*>(out)[row] = make_float4(e0, e1, e2, e3);
}

extern "C" void kernel_launch(void* const* d_in, const int* in_sizes, int n_in,
                              void* d_out, int out_size, void* d_ws, size_t ws_size,
                              hipStream_t stream) {
  const float* x  = (const float*)d_in[0];
  const float* Wp = (const float*)d_in[1];
  const float* bp = (const float*)d_in[2];
  const float* qw = (const float*)d_in[3];
  float* out = (float*)d_out;
  float* A = (float*)d_ws;   // 324 floats
  (void)n_in; (void)out_size; (void)ws_size;

  qprep_kernel<<<1, 256, 0, stream>>>(qw, A);

  const int B = in_sizes[0] / 64;   // 524288 rows
  qmain_kernel<<<B / 256, 256, 0, stream>>>(x, Wp, bp,
                                            (const float4*)A, out);
}

// Round 22
// 35.822 us; speedup vs baseline: 1.0751x; 1.0751x over previous
//
#include <hip/hip_runtime.h>
#include <hip/hip_bf16.h>
#include <cmath>

// Round 22: r20's swizzled-staging qmain, staging via global_load_lds DMA.
//   r20's register-transit staging chains load->ds_write->ds_read per wave
//   and burns 48 transit VGPRs. global_load_lds (width=16) is fire-and-
//   forget: 4 instrs/subtile, LDS dest = uniform base + lane*16 (wave-
//   private, zero barriers), completion via COUNTED vmcnt (never 0 in the
//   steady loop). Read-side XOR swizzle preserved by pre-swizzling the
//   GLOBAL source address (m173): permutes 16B chunks within each fully-
//   covered 1KB -> lines still fully consumed. WAR on buffer reuse closed
//   by lgkmcnt(0)+sched_barrier before reuse-STAGE; TAIL's store event is
//   accounted in the vmcnt schedule (VM(5) after the store).

typedef __attribute__((ext_vector_type(8))) short bf16x8;
typedef __attribute__((ext_vector_type(4))) float f32x4;

// ---- prep kernel: verbatim round-10 (validated r10-r21) ----
__global__ __launch_bounds__(256) void qprep_kernel(
    const float* __restrict__ qw,   // [3][4][2]
    float* __restrict__ A_out)      // [81][4]
{
  __shared__ float sre[16][17];
  __shared__ float sim[16][17];
  __shared__ float M[4][16][16];
  const int tid = threadIdx.x;
  const int col = tid >> 4;
  const int u   = tid & 15;

  sre[col][u] = (u == col) ? 1.0f : 0.0f;
  sim[col][u] = 0.0f;
  __syncthreads();

#pragma unroll
  for (int l = 0; l < 3; ++l) {
#pragma unroll
    for (int w = 0; w < 4; ++w) {
      const int mask = 8 >> w;     // wire 0 = MSB
      float sh, ch, sh2, ch2;
      __sincosf(0.5f * qw[(l * 4 + w) * 2 + 0], &sh, &ch);    // RY
      __sincosf(0.5f * qw[(l * 4 + w) * 2 + 1], &sh2, &ch2);  // RZ
      const int ua = u & ~mask, ub = u | mask;
      const float ar = sre[col][ua], ai = sim[col][ua];
      const float br = sre[col][ub], bi = sim[col][ub];
      __syncthreads();
      float nr, ni;
      if (u & mask) { nr = sh * ar + ch * br; ni = sh * ai + ch * bi; }
      else          { nr = ch * ar - sh * br; ni = ch * ai - sh * bi; }
      float rr, ri;
      if (u & mask) { rr = ch2 * nr - sh2 * ni; ri = ch2 * ni + sh2 * nr; }
      else          { rr = ch2 * nr + sh2 * ni; ri = ch2 * ni - sh2 * nr; }
      sre[col][u] = rr; sim[col][u] = ri;
      __syncthreads();
    }
    int src = u;
    if (src & 1) src ^= 8;
    if (src & 2) src ^= 1;
    if (src & 4) src ^= 2;
    if (src & 8) src ^= 4;
    const float pr = sre[col][src], pi = sim[col][src];
    __syncthreads();
    sre[col][u] = pr; sim[col][u] = pi;
    __syncthreads();
  }

  for (int idx = tid; idx < 1024; idx += 256) {
    const int w = idx >> 8, s = (idx >> 4) & 15, t = idx & 15;
    const int mask = 8 >> w;
    float acc = 0.0f;
#pragma unroll
    for (int uu = 0; uu < 16; ++uu) {
      const float z = (uu & mask) ? -1.0f : 1.0f;
      acc += z * (sre[s][uu] * sre[t][uu] + sim[s][uu] * sim[t][uu]);
    }
    M[w][s][t] = acc;
  }
  __syncthreads();

  for (int idx = tid; idx < 324; idx += 256) {
    const int w = idx & 3, pq = idx >> 2;
    const int p = pq / 9, q = pq % 9;
    const int i0 = p / 3, i1 = p % 3, i2 = q / 3, i3 = q % 3;
    float acc = 0.0f;
#pragma unroll
    for (int comb = 0; comb < 16; ++comb) {
      int s = 0, t = 0;
      float coef = 0.0625f;
      int j;
      j = (comb >> 3) & 1; s |= j << 3; t |= ((i0 == 2) ? (j ^ 1) : j) << 3; if (i0 == 1 && j) coef = -coef;
      j = (comb >> 2) & 1; s |= j << 2; t |= ((i1 == 2) ? (j ^ 1) : j) << 2; if (i1 == 1 && j) coef = -coef;
      j = (comb >> 1) & 1; s |= j << 1; t |= ((i2 == 2) ? (j ^ 1) : j) << 1; if (i2 == 1 && j) coef = -coef;
      j = comb & 1;        s |= j;      t |= ((i3 == 2) ? (j ^ 1) : j);      if (i3 == 1 && j) coef = -coef;
      acc = fmaf(coef, M[w][s][t], acc);
    }
    A_out[idx] = acc;   // layout [pq*4 + w]
  }
}

// pack 8 floats -> bf16x8 via compiler casts (emits v_cvt_pk_bf16_f32)
__device__ __forceinline__ bf16x8 pack8(const float4 va, const float4 vb) {
  union { bf16x8 v; __hip_bfloat16 h[8]; } u;
  u.h[0] = __float2bfloat16(va.x); u.h[1] = __float2bfloat16(va.y);
  u.h[2] = __float2bfloat16(va.z); u.h[3] = __float2bfloat16(va.w);
  u.h[4] = __float2bfloat16(vb.x); u.h[5] = __float2bfloat16(vb.y);
  u.h[6] = __float2bfloat16(vb.z); u.h[7] = __float2bfloat16(vb.w);
  return u.v;
}

__device__ __forceinline__ float ftanh(float a) {
  return 1.0f - 2.0f * __builtin_amdgcn_rcpf(__expf(2.0f * a) + 1.0f);
}

// fire-and-forget 16B/lane DMA: global (per-lane, pre-swizzled) -> LDS linear
__device__ __forceinline__ void gll16(const float* g, float* l) {
  __builtin_amdgcn_global_load_lds(
      (const __attribute__((address_space(1))) void*)g,
      (__attribute__((address_space(3))) void*)l, 16, 0, 0);
}

// ---- STAGE: 4 DMA calls; piece i covers local words i*256 + lane*4.
//      Global source pre-swizzled: g_local = w ^ ((row(w)&7)<<2). ----
#define STAGE(S) {                                                          \
  const float* gb_ = x + (wrow0 + (size_t)((S) * 16)) * 64;                 \
  float* lb_ = sb + ((S) & 1) * 1024;                                       \
  gll16(gb_ + (((0 * 256 + lane * 4) ^ ((((0 * 4) + (lane >> 4)) & 7) << 2))), lb_ + 0 * 256); \
  gll16(gb_ + (((1 * 256 + lane * 4) ^ ((((1 * 4) + (lane >> 4)) & 7) << 2))), lb_ + 1 * 256); \
  gll16(gb_ + (((2 * 256 + lane * 4) ^ ((((2 * 4) + (lane >> 4)) & 7) << 2))), lb_ + 2 * 256); \
  gll16(gb_ + (((3 * 256 + lane * 4) ^ ((((3 * 4) + (lane >> 4)) & 7) << 2))), lb_ + 3 * 256); }

#define VM(N) { asm volatile("s_waitcnt vmcnt(" #N ")" ::: "memory");       \
                __builtin_amdgcn_sched_barrier(0); }
#define LG0() { asm volatile("s_waitcnt lgkmcnt(0)" ::: "memory");          \
                __builtin_amdgcn_sched_barrier(0); }

// ---- CONSUME: swizzled b128 reads -> pack -> 2 MFMA -> scatter (r20) ----
#define CONSUME(S) {                                                        \
  const float* s_ = sb + ((S) & 1) * 1024;                                  \
  const float4 f0 = *reinterpret_cast<const float4*>(s_ + ((cb_ + 0) ^ rw_)); \
  const float4 f1 = *reinterpret_cast<const float4*>(s_ + ((cb_ + 4) ^ rw_)); \
  const float4 f2 = *reinterpret_cast<const float4*>(s_ + ((cb_ + 32) ^ rw_)); \
  const float4 f3 = *reinterpret_cast<const float4*>(s_ + ((cb_ + 36) ^ rw_)); \
  const bf16x8 af0_ = pack8(f0, f1);                                        \
  const bf16x8 af1_ = pack8(f2, f3);                                        \
  f32x4 acc_ = __builtin_amdgcn_mfma_f32_16x16x32_bf16(af0_, wf0, zero, 0, 0, 0); \
  acc_ = __builtin_amdgcn_mfma_f32_16x16x32_bf16(af1_, wf1, acc_, 0, 0, 0); \
  if (arow < 4) {                                                           \
    _Pragma("unroll")                                                       \
    for (int r_ = 0; r_ < 4; ++r_)                                          \
      ap[((((S) & 3) * 16) + kgrp * 4 + r_) * 4 + arow] = acc_[r_];         \
  } }

// ---- TAIL: lane owns row R0+lane (r17-proven fences) ----
#define TAIL(R0) {                                                          \
  asm volatile("s_waitcnt lgkmcnt(0)" ::: "memory");                        \
  __builtin_amdgcn_sched_barrier(0);                                        \
  const float4 ang = *reinterpret_cast<const float4*>(&ap[lane * 4]);       \
  const float t0 = ftanh(ang.x + bp[0]);                                    \
  const float t1 = ftanh(ang.y + bp[1]);                                    \
  const float t2 = ftanh(ang.z + bp[2]);                                    \
  const float t3 = ftanh(ang.w + bp[3]);                                    \
  float c0, s0, c1, s1, c2, s2, c3, s3;                                     \
  __sincosf(t0, &s0, &c0); __sincosf(t1, &s1, &c1);                         \
  __sincosf(t2, &s2, &c2); __sincosf(t3, &s3, &c3);                         \
  const float g[9] = {1.f, c1, s1, c0, c0 * c1, c0 * s1,                    \
                      s0, s0 * c1, s0 * s1};                                \
  const float h[9] = {1.f, c3, s3, c2, c2 * c3, c2 * s3,                    \
                      s2, s2 * c3, s2 * s3};                                \
  float e0 = 0.f, e1 = 0.f, e2 = 0.f, e3 = 0.f;                             \
  _Pragma("unroll")                                                         \
  for (int p_ = 0; p_ < 9; ++p_) {                                          \
    _Pragma("unroll")                                                       \
    for (int q_ = 0; q_ < 9; ++q_) {                                        \
      const float4 a4 = Aws[p_ * 9 + q_];                                   \
      const float tt = g[p_] * h[q_];                                       \
      e0 = fmaf(a4.x, tt, e0); e1 = fmaf(a4.y, tt, e1);                     \
      e2 = fmaf(a4.z, tt, e2); e3 = fmaf(a4.w, tt, e3);                     \
    }                                                                       \
  }                                                                         \
  reinterpret_cast<float4*>(out)[(R0) + lane] =                             \
      make_float4(e0, e1, e2, e3);                                          \
  asm volatile("" ::: "memory"); }

__global__ __launch_bounds__(256)
__attribute__((amdgpu_waves_per_eu(4, 4)))   // 128-VGPR cap
void qmain_kernel(
    const float* __restrict__ x,     // [B][64]
    const float* __restrict__ Wp,    // [4][64]
    const float* __restrict__ bp,    // [4]
    const float4* __restrict__ Aws,  // [81] float4 (d_ws)
    float* __restrict__ out)         // [B][4]
{
  // per wave: sbuf[2][1024] (8KB) + apatch[256] (1KB)
  __shared__ alignas(16) float lds[4 * 2304];   // 36,864 B -> 4 blocks/CU

  const int tid  = threadIdx.x;
  const int lane = tid & 63;
  const int wid  = tid >> 6;
  const int arow = lane & 15;        // x-row within subtile
  const int kgrp = lane >> 4;        // k-group
  float* sb = &lds[wid * 2304];
  float* ap = sb + 2048;

  const size_t wrow0 = ((size_t)blockIdx.x * 4 + wid) * 128;  // 8 subtiles
  const int rw_ = (arow & 7) << 2;
  const int cb_ = arow * 64 + kgrp * 8;

  // B fragment: W^T, cols 0..3 real, 4..15 zero (r13-r21 proven)
  bf16x8 wf0, wf1;
#pragma unroll
  for (int j = 0; j < 8; ++j) {
    if (arow < 4) {
      union { short s; __hip_bfloat16 h; } u0, u1;
      u0.h = __float2bfloat16(Wp[arow * 64 + 0  + kgrp * 8 + j]);
      u1.h = __float2bfloat16(Wp[arow * 64 + 32 + kgrp * 8 + j]);
      wf0[j] = u0.s; wf1[j] = u1.s;
    } else {
      wf0[j] = 0; wf1[j] = 0;
    }
  }
  const f32x4 zero = {0.f, 0.f, 0.f, 0.f};

  const size_t r0 = wrow0;            // tile 0 (subtiles 0-3)
  const size_t r1 = wrow0 + 64;       // tile 1 (subtiles 4-7)

  // vmcnt ledger: STAGE = 4 events; TAIL store = 1 event.
  STAGE(0);                       // q: 0(4)
  STAGE(1);                       // q: 0,1 (8)
  VM(4);  CONSUME(0);             // 0 landed
  LG0();  STAGE(2);               // q: 1,2 (8)   (LG0 closes WAR on buf0)
  VM(4);  CONSUME(1);
  LG0();  STAGE(3);               // q: 2,3 (8)
  VM(4);  CONSUME(2);
  LG0();  STAGE(4);               // q: 3,4 (8)
  VM(4);  CONSUME(3);
  LG0();  STAGE(5);               // q: 4,5 (8)

  TAIL(r0);                       // +store -> q: 4,5,st (9)

  VM(5);  CONSUME(4);             // 4 landed (5's 4 + store remain)
  LG0();  STAGE(6);               // q: 5,st,6 (<=9)
  VM(5);  CONSUME(5);             // 5 landed
  LG0();  STAGE(7);               // q: st,6,7 (<=9)
  VM(4);  CONSUME(6);             // 6 landed (store drains first)
  VM(0);  CONSUME(7);             // all landed

  TAIL(r1);
}

extern "C" void kernel_launch(void* const* d_in, const int* in_sizes, int n_in,
                              void* d_out, int out_size, void* d_ws, size_t ws_size,
                              hipStream_t stream) {
  const float* x  = (const float*)d_in[0];
  const float* Wp = (const float*)d_in[1];
  const float* bp = (const float*)d_in[2];
  const float* qw = (const float*)d_in[3];
  float* out = (float*)d_out;
  float* A = (float*)d_ws;   // 324 floats
  (void)n_in; (void)out_size; (void)ws_size;

  qprep_kernel<<<1, 256, 0, stream>>>(qw, A);

  const int B = in_sizes[0] / 64;   // 524288 rows
  qmain_kernel<<<B / 512, 256, 0, stream>>>(x, Wp, bp,
                                            (const float4*)A, out);
}